// Round 10
// baseline (583.422 us; speedup 1.0000x reference)
//
#include <hip/hip_runtime.h>

#define DD 64
#define ATT_SLOPE 0.2f
#define ACT_SLOPE 0.01f
#define GNPB 16    // nodes per block in gemm (4 per wave)
#define NBSH 7
#define NB   128   // nodes per bucket
#define CAP  3072  // bucket capacity (mean fill 2048, sigma~45 -> 23-sigma slack)

// ---------------- CSR build (bucketed counting sort) ----------------
// edge_index delivered as int32, flat [2,E]: src = ei[e], dst = ei[E+e].
// Self-loops (GATConv add_self_loops=True) are added analytically as the
// last slot of each row. No per-node global atomics; col_src writes are
// confined to per-bucket contiguous regions (L2-local, full-line writebacks).

// K1: append each edge to its dst-bucket as a packed int {dloc:7b | src:17b}.
__global__ void bucket_scatter_kernel(const int* __restrict__ ei, int E,
                                      int* __restrict__ bcur,
                                      int* __restrict__ bucket) {
    int e = blockIdx.x * 256 + threadIdx.x;
    if (e >= E) return;
    int s = ei[e], d = ei[E + e];
    int b = d >> NBSH;
    int pos = atomicAdd(&bcur[b], 1);
    if (pos < CAP) bucket[b * CAP + pos] = s | ((d & (NB - 1)) << 17);
}

// K2: exclusive prefix over buckets of (edges_in_bucket + nodes_in_bucket).
__global__ void bucket_prefix_kernel(const int* __restrict__ bcur,
                                     int* __restrict__ bbase,
                                     int nbuckets, int n) {
    __shared__ int tile[512];
    int t = threadIdx.x;
    int v = 0;
    if (t < nbuckets) {
        int n0 = t << NBSH;
        int nodes = n - n0; if (nodes > NB) nodes = NB;
        int c = bcur[t]; if (c > CAP) c = CAP;
        v = c + nodes;
    }
    tile[t] = v;
    __syncthreads();
    #pragma unroll
    for (int off = 1; off < 512; off <<= 1) {
        int add = (t >= off) ? tile[t - off] : 0;
        __syncthreads();
        tile[t] += add;
        __syncthreads();
    }
    if (t < nbuckets) bbase[t] = tile[t] - v;
}

// K3: per-bucket CSR build. LDS histogram -> LDS scan -> row_ptr (coalesced)
// + self-loop slot + rank-scatter of edges via LDS atomics. All col_src
// writes land in one ~8 KB contiguous region per block.
__global__ __launch_bounds__(256) void bucket_build_kernel(
        const int* __restrict__ bcur, const int* __restrict__ bucket,
        const int* __restrict__ bbase, int* __restrict__ row_ptr,
        int* __restrict__ col_src, int n) {
    __shared__ int ent[CAP];
    __shared__ int hist[NB];
    __shared__ int excl[NB];
    __shared__ int cur[NB];
    int b = blockIdx.x, t = threadIdx.x;
    int n0 = b << NBSH;
    int cnt = bcur[b]; if (cnt > CAP) cnt = CAP;
    int base = bbase[b];

    for (int i = t; i < cnt; i += 256) ent[i] = bucket[b * CAP + i];
    if (t < NB) { hist[t] = 0; cur[t] = 0; }
    __syncthreads();
    for (int i = t; i < cnt; i += 256) atomicAdd(&hist[ent[i] >> 17], 1);
    __syncthreads();

    int v = 0;
    if (t < NB) {
        v = (n0 + t < n) ? (hist[t] + 1) : 0;   // +1 = self-loop slot
        excl[t] = v;
    }
    __syncthreads();
    #pragma unroll
    for (int off = 1; off < NB; off <<= 1) {
        int add = (t < NB && t >= off) ? excl[t - off] : 0;
        __syncthreads();
        if (t < NB) excl[t] += add;
        __syncthreads();
    }
    if (t < NB && n0 + t < n) {
        int incl = excl[t];
        row_ptr[n0 + t + 1] = base + incl;
        col_src[base + incl - 1] = n0 + t;      // self-loop = last slot of row
        excl[t] = incl - v;                     // keep exclusive for scatter
    }
    if (b == 0 && t == 0) row_ptr[0] = 0;
    __syncthreads();

    for (int i = t; i < cnt; i += 256) {
        int p = ent[i];
        int s = p & 0x1FFFF;
        int dl = p >> 17;
        int r = atomicAdd(&cur[dl], 1);
        col_src[base + excl[dl] + r] = s;
    }
}

// ---------------- per-layer kernels ----------------

// h = in @ W.T. Lane j computes output dim j; its weights are W row j --
// 256 B contiguous in global memory, L1-resident after first touch, loaded
// float4 per k-quad inside the loop (no per-lane W array -> no spill).
// x rows are wave-uniform s_loads (4 nodes per wave, 4 independent chains).
__global__ void gemm_alpha_kernel(
        const float* __restrict__ in, const float* __restrict__ W,
        const float* __restrict__ a_src, const float* __restrict__ a_dst,
        float* __restrict__ h, float* __restrict__ as_out,
        float* __restrict__ ad_out, int n_nodes) {
    int t = threadIdx.x;
    int lane = t & 63;
    int w = __builtin_amdgcn_readfirstlane(t >> 6);   // wave-uniform wave id
    int n0 = blockIdx.x * GNPB + w * 4;
    if (n0 >= n_nodes) return;

    float asl = a_src[lane], adl = a_dst[lane];
    const float* wrow = W + (size_t)lane * 64;

    if (n0 + 4 <= n_nodes) {
        const float* x0 = in + (size_t)(n0 + 0) * 64;
        const float* x1 = in + (size_t)(n0 + 1) * 64;
        const float* x2 = in + (size_t)(n0 + 2) * 64;
        const float* x3 = in + (size_t)(n0 + 3) * 64;
        float a0 = 0.f, a1 = 0.f, a2 = 0.f, a3 = 0.f;
        #pragma unroll
        for (int kq = 0; kq < 16; ++kq) {
            float4 wv = *(const float4*)(wrow + kq * 4);   // L1 hit
            float4 xa = *(const float4*)(x0 + kq * 4);     // uniform -> s_load
            float4 xb = *(const float4*)(x1 + kq * 4);
            float4 xc = *(const float4*)(x2 + kq * 4);
            float4 xd = *(const float4*)(x3 + kq * 4);
            a0 = fmaf(xa.x, wv.x, a0); a0 = fmaf(xa.y, wv.y, a0);
            a0 = fmaf(xa.z, wv.z, a0); a0 = fmaf(xa.w, wv.w, a0);
            a1 = fmaf(xb.x, wv.x, a1); a1 = fmaf(xb.y, wv.y, a1);
            a1 = fmaf(xb.z, wv.z, a1); a1 = fmaf(xb.w, wv.w, a1);
            a2 = fmaf(xc.x, wv.x, a2); a2 = fmaf(xc.y, wv.y, a2);
            a2 = fmaf(xc.z, wv.z, a2); a2 = fmaf(xc.w, wv.w, a2);
            a3 = fmaf(xd.x, wv.x, a3); a3 = fmaf(xd.y, wv.y, a3);
            a3 = fmaf(xd.z, wv.z, a3); a3 = fmaf(xd.w, wv.w, a3);
        }
        h[(size_t)(n0 + 0) * 64 + lane] = a0;
        h[(size_t)(n0 + 1) * 64 + lane] = a1;
        h[(size_t)(n0 + 2) * 64 + lane] = a2;
        h[(size_t)(n0 + 3) * 64 + lane] = a3;
        float s[8] = {a0 * asl, a0 * adl, a1 * asl, a1 * adl,
                      a2 * asl, a2 * adl, a3 * asl, a3 * adl};
        #pragma unroll
        for (int m = 32; m >= 1; m >>= 1) {
            #pragma unroll
            for (int i = 0; i < 8; ++i) s[i] += __shfl_xor(s[i], m, 64);
        }
        if (lane == 0) {
            as_out[n0 + 0] = s[0]; ad_out[n0 + 0] = s[1];
            as_out[n0 + 1] = s[2]; ad_out[n0 + 1] = s[3];
            as_out[n0 + 2] = s[4]; ad_out[n0 + 2] = s[5];
            as_out[n0 + 3] = s[6]; ad_out[n0 + 3] = s[7];
        }
    } else {
        for (int r = 0; r < 4; ++r) {
            int node = n0 + r;
            if (node >= n_nodes) break;
            const float* xr = in + (size_t)node * 64;
            float acc = 0.f;
            #pragma unroll
            for (int kq = 0; kq < 16; ++kq) {
                float4 wv = *(const float4*)(wrow + kq * 4);
                float4 xa = *(const float4*)(xr + kq * 4);
                acc = fmaf(xa.x, wv.x, acc); acc = fmaf(xa.y, wv.y, acc);
                acc = fmaf(xa.z, wv.z, acc); acc = fmaf(xa.w, wv.w, acc);
            }
            h[(size_t)node * 64 + lane] = acc;
            float s1 = acc * asl, s2 = acc * adl;
            #pragma unroll
            for (int m = 32; m >= 1; m >>= 1) {
                s1 += __shfl_xor(s1, m, 64);
                s2 += __shfl_xor(s2, m, 64);
            }
            if (lane == 0) { as_out[node] = s1; ad_out[node] = s2; }
        }
    }
}

// One wave per dst node; lane = (group g, float4 chunk u). Depth-3 software
// pipeline (2 edges prefetched ahead per group).
template <bool FUSE_HEAD>
__global__ __launch_bounds__(256) void aggregate_kernel(
        const int* __restrict__ row_ptr, const int* __restrict__ col_src,
        const float* __restrict__ h, const float* __restrict__ as_arr,
        const float* __restrict__ ad_arr, const float* __restrict__ b,
        float* __restrict__ out, const float* __restrict__ Wout,
        const float* __restrict__ bout, int n_nodes) {
    int t = threadIdx.x;
    int w = t >> 6, lane = t & 63;
    int node = blockIdx.x * 4 + w;
    if (node >= n_nodes) return;
    int g = lane >> 4, u = lane & 15;

    int beg = __builtin_amdgcn_readfirstlane(row_ptr[node]);
    int end = __builtin_amdgcn_readfirstlane(row_ptr[node + 1]);
    float adn = ad_arr[node];

    float4 acc = {0.f, 0.f, 0.f, 0.f};
    float lsum = 0.f;
    int e = beg + g;

    int sA = 0; float aA = 0.f; float4 hA = {0.f, 0.f, 0.f, 0.f};
    int sB = 0; float aB = 0.f; float4 hB = {0.f, 0.f, 0.f, 0.f};
    if (e < end) {
        sA = col_src[e];
        aA = as_arr[sA];
        hA = *(const float4*)(h + (size_t)sA * 64 + u * 4);
    }
    if (e + 4 < end) {
        sB = col_src[e + 4];
        aB = as_arr[sB];
        hB = *(const float4*)(h + (size_t)sB * 64 + u * 4);
    }
    while (e < end) {
        int e2 = e + 8;
        int sC = 0; float aC = 0.f; float4 hC = {0.f, 0.f, 0.f, 0.f};
        if (e2 < end) {
            sC = col_src[e2];
            aC = as_arr[sC];
            hC = *(const float4*)(h + (size_t)sC * 64 + u * 4);
        }
        float lg = aA + adn;
        lg = (lg >= 0.f) ? lg : ATT_SLOPE * lg;
        float p = __expf(lg);
        lsum += p;
        acc.x = fmaf(p, hA.x, acc.x);
        acc.y = fmaf(p, hA.y, acc.y);
        acc.z = fmaf(p, hA.z, acc.z);
        acc.w = fmaf(p, hA.w, acc.w);
        sA = sB; aA = aB; hA = hB;
        sB = sC; aB = aC; hB = hC;
        e += 4;
    }
    #pragma unroll
    for (int m = 16; m <= 32; m <<= 1) {
        acc.x += __shfl_xor(acc.x, m, 64);
        acc.y += __shfl_xor(acc.y, m, 64);
        acc.z += __shfl_xor(acc.z, m, 64);
        acc.w += __shfl_xor(acc.w, m, 64);
        lsum  += __shfl_xor(lsum, m, 64);
    }
    float inv = 1.f / lsum;
    const float4 bv4 = *(const float4*)(b + u * 4);
    float4 o;
    o.x = acc.x * inv + bv4.x; o.x = (o.x >= 0.f) ? o.x : ACT_SLOPE * o.x;
    o.y = acc.y * inv + bv4.y; o.y = (o.y >= 0.f) ? o.y : ACT_SLOPE * o.y;
    o.z = acc.z * inv + bv4.z; o.z = (o.z >= 0.f) ? o.z : ACT_SLOPE * o.z;
    o.w = acc.w * inv + bv4.w; o.w = (o.w >= 0.f) ? o.w : ACT_SLOPE * o.w;

    if (FUSE_HEAD) {
        const float4 wv = *(const float4*)(Wout + u * 4);
        float pd = o.x * wv.x + o.y * wv.y + o.z * wv.z + o.w * wv.w;
        #pragma unroll
        for (int m = 1; m <= 8; m <<= 1) pd += __shfl_xor(pd, m, 64);
        if (lane == 0) out[node] = pd + bout[0];
    } else {
        if (g == 0) *(float4*)(out + (size_t)node * 64 + u * 4) = o;
    }
}

// ---------------- launch ----------------

extern "C" void kernel_launch(void* const* d_in, const int* in_sizes, int n_in,
                              void* d_out, int out_size, void* d_ws, size_t ws_size,
                              hipStream_t stream) {
    const float* x     = (const float*)d_in[0];
    const float* W[3]  = {(const float*)d_in[1], (const float*)d_in[5], (const float*)d_in[9]};
    const float* as[3] = {(const float*)d_in[2], (const float*)d_in[6], (const float*)d_in[10]};
    const float* ad[3] = {(const float*)d_in[3], (const float*)d_in[7], (const float*)d_in[11]};
    const float* bv[3] = {(const float*)d_in[4], (const float*)d_in[8], (const float*)d_in[12]};
    const float* Wout  = (const float*)d_in[13];
    const float* bout  = (const float*)d_in[14];
    const int*   ei    = (const int*)d_in[15];   // int64 reference -> delivered int32

    const int N  = in_sizes[0] / DD;
    const int E  = in_sizes[15] / 2;
    const int ET = E + N;
    const int NBK = (N + NB - 1) >> NBSH;        // buckets (391 for N=50k)

    // workspace layout (~30 MB; 256 B aligned)
    char* ws = (char*)d_ws;
    size_t off = 0;
    auto alloc = [&](size_t bytes) {
        void* p = ws + off;
        off = (off + bytes + 255) & ~(size_t)255;
        return p;
    };
    int*   col_src = (int*)alloc((size_t)ET * 4);
    int*   row_ptr = (int*)alloc((size_t)(N + 1) * 4);
    float* as_arr  = (float*)alloc((size_t)N * 4);
    float* ad_arr  = (float*)alloc((size_t)N * 4);
    float* hbuf    = (float*)alloc((size_t)N * DD * 4);
    float* obuf    = (float*)alloc((size_t)N * DD * 4);
    (void)ws_size;

    // CSR-build temporaries alias the big layer buffers (both first written
    // by gemm/aggregate, which launch after the CSR build completes):
    int* bucket = (int*)hbuf;            // NBK*CAP ints (4.8 MB < 12.8 MB)
    int* bcur   = (int*)obuf;            // NBK ints
    int* bbase  = bcur + 512;            // NBK ints

    int gridE = (E + 255) / 256;
    int gridG = (N + GNPB - 1) / GNPB;
    int grid4 = (N + 3) / 4;

    // CSR build (dst identical across the 3 layers -> build once per call)
    hipMemsetAsync(bcur, 0, (size_t)NBK * 4, stream);
    bucket_scatter_kernel<<<gridE, 256, 0, stream>>>(ei, E, bcur, bucket);
    bucket_prefix_kernel<<<1, 512, 0, stream>>>(bcur, bbase, NBK, N);
    bucket_build_kernel<<<NBK, 256, 0, stream>>>(bcur, bucket, bbase,
                                                 row_ptr, col_src, N);

    // 3 GAT layers; head fused into the last aggregate.
    const float* cur = x;
    for (int L = 0; L < 3; ++L) {
        gemm_alpha_kernel<<<gridG, 256, 0, stream>>>(cur, W[L], as[L], ad[L],
                                                     hbuf, as_arr, ad_arr, N);
        if (L < 2) {
            aggregate_kernel<false><<<grid4, 256, 0, stream>>>(
                row_ptr, col_src, hbuf, as_arr, ad_arr, bv[L], obuf,
                nullptr, nullptr, N);
        } else {
            aggregate_kernel<true><<<grid4, 256, 0, stream>>>(
                row_ptr, col_src, hbuf, as_arr, ad_arr, bv[L], (float*)d_out,
                Wout, bout, N);
        }
        cur = obuf;
    }
}

// Round 11
// 328.662 us; speedup vs baseline: 1.7751x; 1.7751x over previous
//
#include <hip/hip_runtime.h>
#include <hip/hip_fp16.h>

#define DD 64
#define ATT_SLOPE 0.2f
#define ACT_SLOPE 0.01f
#define GNPB 16   // nodes per block in gemm (4 per wave)

// ---------------- CSR build ----------------
// edge_index delivered as int32, flat [2,E]: src = ei[e], dst = ei[E+e].
// Self-loops (GATConv add_self_loops=True) are added analytically: the scan
// gives each row one extra slot; scan_final writes the loop into the row's
// last slot. Per-node atomics (50k addresses) -- NOT few-bucket cursors:
// R10 showed 391-cursor atomics serialize catastrophically (282 us).

__global__ void count_kernel(const int* __restrict__ ei, int E,
                             int* __restrict__ counts, int* __restrict__ rank) {
    int e = blockIdx.x * blockDim.x + threadIdx.x;
    if (e >= E) return;
    int d = ei[E + e];
    rank[e] = atomicAdd(&counts[d], 1);
}

// Scan k1: per-block local exclusive scan of (counts[i]+1) -> scan_tmp,
// block total -> blk.
__global__ void scan_blocks_kernel(const int* __restrict__ counts,
                                   int* __restrict__ scan_tmp,
                                   int* __restrict__ blk, int n) {
    __shared__ int tile[256];
    int t = threadIdx.x;
    int i = blockIdx.x * 256 + t;
    int v = (i < n) ? (counts[i] + 1) : 0;     // +1 = self-loop slot
    tile[t] = v;
    __syncthreads();
    #pragma unroll
    for (int off = 1; off < 256; off <<= 1) {
        int add = (t >= off) ? tile[t - off] : 0;
        __syncthreads();
        tile[t] += add;
        __syncthreads();
    }
    if (i < n) scan_tmp[i] = tile[t] - v;
    if (t == 255) blk[blockIdx.x] = tile[255];
}

// Scan k2 (fused carry + fixup): every block redundantly scans the <=256
// block totals in LDS, picks its carry, writes row_ptr and the self-loop.
__global__ void scan_final_kernel(const int* __restrict__ counts,
                                  const int* __restrict__ scan_tmp,
                                  const int* __restrict__ blk,
                                  int* __restrict__ row_ptr,
                                  int* __restrict__ col_src, int n, int nb) {
    __shared__ int tile[256];
    int t = threadIdx.x;
    int v = (t < nb) ? blk[t] : 0;
    tile[t] = v;
    __syncthreads();
    #pragma unroll
    for (int off = 1; off < 256; off <<= 1) {
        int add = (t >= off) ? tile[t - off] : 0;
        __syncthreads();
        tile[t] += add;
        __syncthreads();
    }
    int carry = (blockIdx.x > 0) ? tile[blockIdx.x - 1] : 0;
    int i = blockIdx.x * 256 + t;
    if (i >= n) return;
    int excl = scan_tmp[i] + carry;
    int nxt = excl + counts[i] + 1;
    row_ptr[i + 1] = nxt;
    if (i == 0) row_ptr[0] = 0;
    col_src[nxt - 1] = i;            // self-loop occupies the row's last slot
}

// Atomic-free scatter of the E real edges via precomputed rank.
__global__ void scatter_kernel(const int* __restrict__ ei, int E,
                               const int* __restrict__ row_ptr,
                               const int* __restrict__ rank,
                               int* __restrict__ col_src) {
    int e = blockIdx.x * blockDim.x + threadIdx.x;
    if (e >= E) return;
    int s = ei[e], d = ei[E + e];
    col_src[row_ptr[d] + rank[e]] = s;
}

// ---------------- per-layer kernels ----------------

// h = in @ W.T. Lane j computes output dim j; weights = W row j (256 B
// contiguous, L1-resident), x rows are wave-uniform s_loads. h is written
// in FP16 (halves the aggregate's gather traffic); alpha dots stay fp32.
__global__ void gemm_alpha_kernel(
        const float* __restrict__ in, const float* __restrict__ W,
        const float* __restrict__ a_src, const float* __restrict__ a_dst,
        __half* __restrict__ h, float* __restrict__ as_out,
        float* __restrict__ ad_out, int n_nodes) {
    int t = threadIdx.x;
    int lane = t & 63;
    int w = __builtin_amdgcn_readfirstlane(t >> 6);   // wave-uniform wave id
    int n0 = blockIdx.x * GNPB + w * 4;
    if (n0 >= n_nodes) return;

    float asl = a_src[lane], adl = a_dst[lane];
    const float* wrow = W + (size_t)lane * 64;

    if (n0 + 4 <= n_nodes) {
        const float* x0 = in + (size_t)(n0 + 0) * 64;
        const float* x1 = in + (size_t)(n0 + 1) * 64;
        const float* x2 = in + (size_t)(n0 + 2) * 64;
        const float* x3 = in + (size_t)(n0 + 3) * 64;
        float a0 = 0.f, a1 = 0.f, a2 = 0.f, a3 = 0.f;
        #pragma unroll
        for (int kq = 0; kq < 16; ++kq) {
            float4 wv = *(const float4*)(wrow + kq * 4);   // L1 hit
            float4 xa = *(const float4*)(x0 + kq * 4);     // uniform -> s_load
            float4 xb = *(const float4*)(x1 + kq * 4);
            float4 xc = *(const float4*)(x2 + kq * 4);
            float4 xd = *(const float4*)(x3 + kq * 4);
            a0 = fmaf(xa.x, wv.x, a0); a0 = fmaf(xa.y, wv.y, a0);
            a0 = fmaf(xa.z, wv.z, a0); a0 = fmaf(xa.w, wv.w, a0);
            a1 = fmaf(xb.x, wv.x, a1); a1 = fmaf(xb.y, wv.y, a1);
            a1 = fmaf(xb.z, wv.z, a1); a1 = fmaf(xb.w, wv.w, a1);
            a2 = fmaf(xc.x, wv.x, a2); a2 = fmaf(xc.y, wv.y, a2);
            a2 = fmaf(xc.z, wv.z, a2); a2 = fmaf(xc.w, wv.w, a2);
            a3 = fmaf(xd.x, wv.x, a3); a3 = fmaf(xd.y, wv.y, a3);
            a3 = fmaf(xd.z, wv.z, a3); a3 = fmaf(xd.w, wv.w, a3);
        }
        h[(size_t)(n0 + 0) * 64 + lane] = __float2half(a0);
        h[(size_t)(n0 + 1) * 64 + lane] = __float2half(a1);
        h[(size_t)(n0 + 2) * 64 + lane] = __float2half(a2);
        h[(size_t)(n0 + 3) * 64 + lane] = __float2half(a3);
        float s[8] = {a0 * asl, a0 * adl, a1 * asl, a1 * adl,
                      a2 * asl, a2 * adl, a3 * asl, a3 * adl};
        #pragma unroll
        for (int m = 32; m >= 1; m >>= 1) {
            #pragma unroll
            for (int i = 0; i < 8; ++i) s[i] += __shfl_xor(s[i], m, 64);
        }
        if (lane == 0) {
            as_out[n0 + 0] = s[0]; ad_out[n0 + 0] = s[1];
            as_out[n0 + 1] = s[2]; ad_out[n0 + 1] = s[3];
            as_out[n0 + 2] = s[4]; ad_out[n0 + 2] = s[5];
            as_out[n0 + 3] = s[6]; ad_out[n0 + 3] = s[7];
        }
    } else {
        for (int r = 0; r < 4; ++r) {
            int node = n0 + r;
            if (node >= n_nodes) break;
            const float* xr = in + (size_t)node * 64;
            float acc = 0.f;
            #pragma unroll
            for (int kq = 0; kq < 16; ++kq) {
                float4 wv = *(const float4*)(wrow + kq * 4);
                float4 xa = *(const float4*)(xr + kq * 4);
                acc = fmaf(xa.x, wv.x, acc); acc = fmaf(xa.y, wv.y, acc);
                acc = fmaf(xa.z, wv.z, acc); acc = fmaf(xa.w, wv.w, acc);
            }
            h[(size_t)node * 64 + lane] = __float2half(acc);
            float s1 = acc * asl, s2 = acc * adl;
            #pragma unroll
            for (int m = 32; m >= 1; m >>= 1) {
                s1 += __shfl_xor(s1, m, 64);
                s2 += __shfl_xor(s2, m, 64);
            }
            if (lane == 0) { as_out[node] = s1; ad_out[node] = s2; }
        }
    }
}

// One wave per dst node; lane = (group g, 8B-chunk u): row = 64 fp16 =
// 128 B, gathered as uint2 (4 halves) per lane. Depth-3 software pipeline.
// Accumulation in fp32; softmax denominators fp32.
template <bool FUSE_HEAD>
__global__ __launch_bounds__(256) void aggregate_kernel(
        const int* __restrict__ row_ptr, const int* __restrict__ col_src,
        const __half* __restrict__ h, const float* __restrict__ as_arr,
        const float* __restrict__ ad_arr, const float* __restrict__ b,
        float* __restrict__ out, const float* __restrict__ Wout,
        const float* __restrict__ bout, int n_nodes) {
    int t = threadIdx.x;
    int w = t >> 6, lane = t & 63;
    int node = blockIdx.x * 4 + w;
    if (node >= n_nodes) return;
    int g = lane >> 4, u = lane & 15;

    int beg = __builtin_amdgcn_readfirstlane(row_ptr[node]);
    int end = __builtin_amdgcn_readfirstlane(row_ptr[node + 1]);
    float adn = ad_arr[node];

    float4 acc = {0.f, 0.f, 0.f, 0.f};
    float lsum = 0.f;
    int e = beg + g;

    uint2 rA = {0, 0}, rB = {0, 0};
    float aA = 0.f, aB = 0.f;
    if (e < end) {
        int sA = col_src[e];
        aA = as_arr[sA];
        rA = *(const uint2*)(h + (size_t)sA * 64 + u * 4);
    }
    if (e + 4 < end) {
        int sB = col_src[e + 4];
        aB = as_arr[sB];
        rB = *(const uint2*)(h + (size_t)sB * 64 + u * 4);
    }
    while (e < end) {
        int e2 = e + 8;
        uint2 rC = {0, 0}; float aC = 0.f;
        if (e2 < end) {
            int sC = col_src[e2];
            aC = as_arr[sC];
            rC = *(const uint2*)(h + (size_t)sC * 64 + u * 4);
        }
        float lg = aA + adn;
        lg = (lg >= 0.f) ? lg : ATT_SLOPE * lg;
        float p = __expf(lg);
        lsum += p;
        float2 f0 = __half22float2(*(const __half2*)&rA.x);
        float2 f1 = __half22float2(*(const __half2*)&rA.y);
        acc.x = fmaf(p, f0.x, acc.x);
        acc.y = fmaf(p, f0.y, acc.y);
        acc.z = fmaf(p, f1.x, acc.z);
        acc.w = fmaf(p, f1.y, acc.w);
        rA = rB; aA = aB;
        rB = rC; aB = aC;
        e += 4;
    }
    #pragma unroll
    for (int m = 16; m <= 32; m <<= 1) {
        acc.x += __shfl_xor(acc.x, m, 64);
        acc.y += __shfl_xor(acc.y, m, 64);
        acc.z += __shfl_xor(acc.z, m, 64);
        acc.w += __shfl_xor(acc.w, m, 64);
        lsum  += __shfl_xor(lsum, m, 64);
    }
    float inv = 1.f / lsum;
    const float4 bv4 = *(const float4*)(b + u * 4);
    float4 o;
    o.x = acc.x * inv + bv4.x; o.x = (o.x >= 0.f) ? o.x : ACT_SLOPE * o.x;
    o.y = acc.y * inv + bv4.y; o.y = (o.y >= 0.f) ? o.y : ACT_SLOPE * o.y;
    o.z = acc.z * inv + bv4.z; o.z = (o.z >= 0.f) ? o.z : ACT_SLOPE * o.z;
    o.w = acc.w * inv + bv4.w; o.w = (o.w >= 0.f) ? o.w : ACT_SLOPE * o.w;

    if (FUSE_HEAD) {
        const float4 wv = *(const float4*)(Wout + u * 4);
        float pd = o.x * wv.x + o.y * wv.y + o.z * wv.z + o.w * wv.w;
        #pragma unroll
        for (int m = 1; m <= 8; m <<= 1) pd += __shfl_xor(pd, m, 64);
        if (lane == 0) out[node] = pd + bout[0];
    } else {
        if (g == 0) *(float4*)(out + (size_t)node * 64 + u * 4) = o;
    }
}

// ---------------- launch ----------------

extern "C" void kernel_launch(void* const* d_in, const int* in_sizes, int n_in,
                              void* d_out, int out_size, void* d_ws, size_t ws_size,
                              hipStream_t stream) {
    const float* x     = (const float*)d_in[0];
    const float* W[3]  = {(const float*)d_in[1], (const float*)d_in[5], (const float*)d_in[9]};
    const float* as[3] = {(const float*)d_in[2], (const float*)d_in[6], (const float*)d_in[10]};
    const float* ad[3] = {(const float*)d_in[3], (const float*)d_in[7], (const float*)d_in[11]};
    const float* bv[3] = {(const float*)d_in[4], (const float*)d_in[8], (const float*)d_in[12]};
    const float* Wout  = (const float*)d_in[13];
    const float* bout  = (const float*)d_in[14];
    const int*   ei    = (const int*)d_in[15];   // int64 reference -> delivered int32

    const int N  = in_sizes[0] / DD;
    const int E  = in_sizes[15] / 2;
    const int ET = E + N;

    // workspace layout (~25 MB; 256 B aligned)
    char* ws = (char*)d_ws;
    size_t off = 0;
    auto alloc = [&](size_t bytes) {
        void* p = ws + off;
        off = (off + bytes + 255) & ~(size_t)255;
        return p;
    };
    int*    col_src = (int*)alloc((size_t)ET * 4);
    int*    counts  = (int*)alloc((size_t)N * 4);
    int*    row_ptr = (int*)alloc((size_t)(N + 1) * 4);
    float*  as_arr  = (float*)alloc((size_t)N * 4);
    float*  ad_arr  = (float*)alloc((size_t)N * 4);
    __half* hbuf    = (__half*)alloc((size_t)N * DD * 2);   // fp16 h (6.4 MB)
    float*  obuf    = (float*)alloc((size_t)N * DD * 4);    // fp32 activations
    (void)ws_size;

    // CSR-build temporaries alias the big layer buffers (both first written
    // by gemm/aggregate, which launch after the CSR build completes):
    int* rank     = (int*)hbuf;          // E ints (3.2 MB < 6.4 MB)
    int* scan_tmp = (int*)obuf;          // N ints
    int* blk      = scan_tmp + N;        // <=256 ints

    int gridE = (E + 255) / 256;
    int gridG = (N + GNPB - 1) / GNPB;
    int grid4 = (N + 3) / 4;
    int nb    = (N + 255) / 256;

    // CSR build (dst identical across the 3 layers -> build once per call)
    hipMemsetAsync(counts, 0, (size_t)N * 4, stream);
    count_kernel<<<gridE, 256, 0, stream>>>(ei, E, counts, rank);
    scan_blocks_kernel<<<nb, 256, 0, stream>>>(counts, scan_tmp, blk, N);
    scan_final_kernel<<<nb, 256, 0, stream>>>(counts, scan_tmp, blk, row_ptr,
                                              col_src, N, nb);
    scatter_kernel<<<gridE, 256, 0, stream>>>(ei, E, row_ptr, rank, col_src);

    // 3 GAT layers; head fused into the last aggregate.
    const float* cur = x;
    for (int L = 0; L < 3; ++L) {
        gemm_alpha_kernel<<<gridG, 256, 0, stream>>>(cur, W[L], as[L], ad[L],
                                                     hbuf, as_arr, ad_arr, N);
        if (L < 2) {
            aggregate_kernel<false><<<grid4, 256, 0, stream>>>(
                row_ptr, col_src, hbuf, as_arr, ad_arr, bv[L], obuf,
                nullptr, nullptr, N);
        } else {
            aggregate_kernel<true><<<grid4, 256, 0, stream>>>(
                row_ptr, col_src, hbuf, as_arr, ad_arr, bv[L], (float*)d_out,
                Wout, bout, N);
        }
        cur = obuf;
    }
}

// Round 12
// 312.085 us; speedup vs baseline: 1.8694x; 1.0531x over previous
//
#include <hip/hip_runtime.h>
#include <hip/hip_fp16.h>

#define DD 64
#define ATT_SLOPE 0.2f
#define ACT_SLOPE 0.01f
#define GNPB 32   // nodes per block in gemm (8 per wave)

// ---------------- CSR build ----------------
// edge_index delivered as int32, flat [2,E]: src = ei[e], dst = ei[E+e].
// Self-loops (GATConv add_self_loops=True) are added analytically: the scan
// gives each row one extra slot; scan_final writes the loop into the row's
// last slot. Per-node atomics (50k addresses) -- NOT few-bucket cursors:
// R10 showed 391-cursor atomics serialize catastrophically (282 us).

__global__ void count_kernel(const int* __restrict__ ei, int E,
                             int* __restrict__ counts, int* __restrict__ rank) {
    int e = blockIdx.x * blockDim.x + threadIdx.x;
    if (e >= E) return;
    int d = ei[E + e];
    rank[e] = atomicAdd(&counts[d], 1);
}

// Scan k1: per-block local exclusive scan of (counts[i]+1) -> scan_tmp,
// block total -> blk.
__global__ void scan_blocks_kernel(const int* __restrict__ counts,
                                   int* __restrict__ scan_tmp,
                                   int* __restrict__ blk, int n) {
    __shared__ int tile[256];
    int t = threadIdx.x;
    int i = blockIdx.x * 256 + t;
    int v = (i < n) ? (counts[i] + 1) : 0;     // +1 = self-loop slot
    tile[t] = v;
    __syncthreads();
    #pragma unroll
    for (int off = 1; off < 256; off <<= 1) {
        int add = (t >= off) ? tile[t - off] : 0;
        __syncthreads();
        tile[t] += add;
        __syncthreads();
    }
    if (i < n) scan_tmp[i] = tile[t] - v;
    if (t == 255) blk[blockIdx.x] = tile[255];
}

// Scan k2 (fused carry + fixup): every block redundantly scans the <=256
// block totals in LDS, picks its carry, writes row_ptr and the self-loop.
__global__ void scan_final_kernel(const int* __restrict__ counts,
                                  const int* __restrict__ scan_tmp,
                                  const int* __restrict__ blk,
                                  int* __restrict__ row_ptr,
                                  int* __restrict__ col_src, int n, int nb) {
    __shared__ int tile[256];
    int t = threadIdx.x;
    int v = (t < nb) ? blk[t] : 0;
    tile[t] = v;
    __syncthreads();
    #pragma unroll
    for (int off = 1; off < 256; off <<= 1) {
        int add = (t >= off) ? tile[t - off] : 0;
        __syncthreads();
        tile[t] += add;
        __syncthreads();
    }
    int carry = (blockIdx.x > 0) ? tile[blockIdx.x - 1] : 0;
    int i = blockIdx.x * 256 + t;
    if (i >= n) return;
    int excl = scan_tmp[i] + carry;
    int nxt = excl + counts[i] + 1;
    row_ptr[i + 1] = nxt;
    if (i == 0) row_ptr[0] = 0;
    col_src[nxt - 1] = i;            // self-loop occupies the row's last slot
}

// Atomic-free scatter of the E real edges via precomputed rank.
__global__ void scatter_kernel(const int* __restrict__ ei, int E,
                               const int* __restrict__ row_ptr,
                               const int* __restrict__ rank,
                               int* __restrict__ col_src) {
    int e = blockIdx.x * blockDim.x + threadIdx.x;
    if (e >= E) return;
    int s = ei[e], d = ei[E + e];
    col_src[row_ptr[d] + rank[e]] = s;
}

// ---------------- per-layer kernels ----------------

// h = in @ W.T. Lane j computes output dim j; weights = W row j (256 B
// contiguous, L1-resident). 8 nodes per wave: wrow load amortized over 8
// independent FMA chains; x rows are wave-uniform s_loads. h written fp16.
__global__ void gemm_alpha_kernel(
        const float* __restrict__ in, const float* __restrict__ W,
        const float* __restrict__ a_src, const float* __restrict__ a_dst,
        __half* __restrict__ h, float* __restrict__ as_out,
        float* __restrict__ ad_out, int n_nodes) {
    int t = threadIdx.x;
    int lane = t & 63;
    int w = __builtin_amdgcn_readfirstlane(t >> 6);   // wave-uniform wave id
    int n0 = blockIdx.x * GNPB + w * 8;
    if (n0 >= n_nodes) return;

    float asl = a_src[lane], adl = a_dst[lane];
    const float* wrow = W + (size_t)lane * 64;

    if (n0 + 8 <= n_nodes) {
        const float* xp[8];
        #pragma unroll
        for (int r = 0; r < 8; ++r) xp[r] = in + (size_t)(n0 + r) * 64;
        float a[8] = {0.f, 0.f, 0.f, 0.f, 0.f, 0.f, 0.f, 0.f};
        #pragma unroll
        for (int kq = 0; kq < 16; ++kq) {
            float4 wv = *(const float4*)(wrow + kq * 4);   // L1 hit
            #pragma unroll
            for (int r = 0; r < 8; ++r) {
                float4 xv = *(const float4*)(xp[r] + kq * 4);  // uniform -> s_load
                a[r] = fmaf(xv.x, wv.x, a[r]); a[r] = fmaf(xv.y, wv.y, a[r]);
                a[r] = fmaf(xv.z, wv.z, a[r]); a[r] = fmaf(xv.w, wv.w, a[r]);
            }
        }
        #pragma unroll
        for (int r = 0; r < 8; ++r)
            h[(size_t)(n0 + r) * 64 + lane] = __float2half(a[r]);
        float s[16];
        #pragma unroll
        for (int r = 0; r < 8; ++r) { s[2 * r] = a[r] * asl; s[2 * r + 1] = a[r] * adl; }
        #pragma unroll
        for (int m = 32; m >= 1; m >>= 1) {
            #pragma unroll
            for (int i = 0; i < 16; ++i) s[i] += __shfl_xor(s[i], m, 64);
        }
        if (lane == 0) {
            #pragma unroll
            for (int r = 0; r < 8; ++r) {
                as_out[n0 + r] = s[2 * r];
                ad_out[n0 + r] = s[2 * r + 1];
            }
        }
    } else {
        for (int r = 0; r < 8; ++r) {
            int node = n0 + r;
            if (node >= n_nodes) break;
            const float* xr = in + (size_t)node * 64;
            float acc = 0.f;
            #pragma unroll
            for (int kq = 0; kq < 16; ++kq) {
                float4 wv = *(const float4*)(wrow + kq * 4);
                float4 xa = *(const float4*)(xr + kq * 4);
                acc = fmaf(xa.x, wv.x, acc); acc = fmaf(xa.y, wv.y, acc);
                acc = fmaf(xa.z, wv.z, acc); acc = fmaf(xa.w, wv.w, acc);
            }
            h[(size_t)node * 64 + lane] = __float2half(acc);
            float s1 = acc * asl, s2 = acc * adl;
            #pragma unroll
            for (int m = 32; m >= 1; m >>= 1) {
                s1 += __shfl_xor(s1, m, 64);
                s2 += __shfl_xor(s2, m, 64);
            }
            if (lane == 0) { as_out[node] = s1; ad_out[node] = s2; }
        }
    }
}

// One wave per dst node; 8 groups of 8 lanes. Lane u in a group holds a
// 16 B uint4 chunk (8 halves) of the 128 B fp16 row -> 8 edges in flight
// per wave. Depth-3 pipeline; with avg 17 edges/row the prologue covers
// almost the entire row. fp32 accumulation (8 floats/lane).
template <bool FUSE_HEAD>
__global__ __launch_bounds__(256) void aggregate_kernel(
        const int* __restrict__ row_ptr, const int* __restrict__ col_src,
        const __half* __restrict__ h, const float* __restrict__ as_arr,
        const float* __restrict__ ad_arr, const float* __restrict__ b,
        float* __restrict__ out, const float* __restrict__ Wout,
        const float* __restrict__ bout, int n_nodes) {
    int t = threadIdx.x;
    int w = t >> 6, lane = t & 63;
    int node = blockIdx.x * 4 + w;
    if (node >= n_nodes) return;
    int g = lane >> 3, u = lane & 7;

    int beg = __builtin_amdgcn_readfirstlane(row_ptr[node]);
    int end = __builtin_amdgcn_readfirstlane(row_ptr[node + 1]);
    float adn = ad_arr[node];

    float acc[8] = {0.f, 0.f, 0.f, 0.f, 0.f, 0.f, 0.f, 0.f};
    float lsum = 0.f;
    int e = beg + g;

    uint4 rA = {0, 0, 0, 0}, rB = {0, 0, 0, 0};
    float aA = 0.f, aB = 0.f;
    if (e < end) {
        int s = col_src[e];
        aA = as_arr[s];
        rA = *(const uint4*)(h + (size_t)s * 64 + u * 8);
    }
    if (e + 8 < end) {
        int s = col_src[e + 8];
        aB = as_arr[s];
        rB = *(const uint4*)(h + (size_t)s * 64 + u * 8);
    }
    while (e < end) {
        int e2 = e + 16;
        uint4 rC = {0, 0, 0, 0}; float aC = 0.f;
        if (e2 < end) {
            int s = col_src[e2];
            aC = as_arr[s];
            rC = *(const uint4*)(h + (size_t)s * 64 + u * 8);
        }
        float lg = aA + adn;
        lg = (lg >= 0.f) ? lg : ATT_SLOPE * lg;
        float p = __expf(lg);
        lsum += p;
        float2 f0 = __half22float2(*(const __half2*)&rA.x);
        float2 f1 = __half22float2(*(const __half2*)&rA.y);
        float2 f2 = __half22float2(*(const __half2*)&rA.z);
        float2 f3 = __half22float2(*(const __half2*)&rA.w);
        acc[0] = fmaf(p, f0.x, acc[0]); acc[1] = fmaf(p, f0.y, acc[1]);
        acc[2] = fmaf(p, f1.x, acc[2]); acc[3] = fmaf(p, f1.y, acc[3]);
        acc[4] = fmaf(p, f2.x, acc[4]); acc[5] = fmaf(p, f2.y, acc[5]);
        acc[6] = fmaf(p, f3.x, acc[6]); acc[7] = fmaf(p, f3.y, acc[7]);
        rA = rB; aA = aB;
        rB = rC; aB = aC;
        e += 8;
    }
    // combine the 8 groups (lanes u, u+8, ..., u+56)
    #pragma unroll
    for (int m = 8; m <= 32; m <<= 1) {
        #pragma unroll
        for (int i = 0; i < 8; ++i) acc[i] += __shfl_xor(acc[i], m, 64);
        lsum += __shfl_xor(lsum, m, 64);
    }
    float inv = 1.f / lsum;
    const float4 b0 = *(const float4*)(b + u * 8);
    const float4 b1 = *(const float4*)(b + u * 8 + 4);
    float o[8];
    o[0] = acc[0] * inv + b0.x; o[1] = acc[1] * inv + b0.y;
    o[2] = acc[2] * inv + b0.z; o[3] = acc[3] * inv + b0.w;
    o[4] = acc[4] * inv + b1.x; o[5] = acc[5] * inv + b1.y;
    o[6] = acc[6] * inv + b1.z; o[7] = acc[7] * inv + b1.w;
    #pragma unroll
    for (int i = 0; i < 8; ++i) o[i] = (o[i] >= 0.f) ? o[i] : ACT_SLOPE * o[i];

    if (FUSE_HEAD) {
        const float4 w0 = *(const float4*)(Wout + u * 8);
        const float4 w1 = *(const float4*)(Wout + u * 8 + 4);
        float pd = o[0] * w0.x + o[1] * w0.y + o[2] * w0.z + o[3] * w0.w
                 + o[4] * w1.x + o[5] * w1.y + o[6] * w1.z + o[7] * w1.w;
        #pragma unroll
        for (int m = 1; m <= 4; m <<= 1) pd += __shfl_xor(pd, m, 64);
        if (lane == 0) out[node] = pd + bout[0];
    } else if (g == 0) {
        float4 v0 = {o[0], o[1], o[2], o[3]};
        float4 v1 = {o[4], o[5], o[6], o[7]};
        *(float4*)(out + (size_t)node * 64 + u * 8) = v0;
        *(float4*)(out + (size_t)node * 64 + u * 8 + 4) = v1;
    }
}

// ---------------- launch ----------------

extern "C" void kernel_launch(void* const* d_in, const int* in_sizes, int n_in,
                              void* d_out, int out_size, void* d_ws, size_t ws_size,
                              hipStream_t stream) {
    const float* x     = (const float*)d_in[0];
    const float* W[3]  = {(const float*)d_in[1], (const float*)d_in[5], (const float*)d_in[9]};
    const float* as[3] = {(const float*)d_in[2], (const float*)d_in[6], (const float*)d_in[10]};
    const float* ad[3] = {(const float*)d_in[3], (const float*)d_in[7], (const float*)d_in[11]};
    const float* bv[3] = {(const float*)d_in[4], (const float*)d_in[8], (const float*)d_in[12]};
    const float* Wout  = (const float*)d_in[13];
    const float* bout  = (const float*)d_in[14];
    const int*   ei    = (const int*)d_in[15];   // int64 reference -> delivered int32

    const int N  = in_sizes[0] / DD;
    const int E  = in_sizes[15] / 2;
    const int ET = E + N;

    // workspace layout (~25 MB; 256 B aligned)
    char* ws = (char*)d_ws;
    size_t off = 0;
    auto alloc = [&](size_t bytes) {
        void* p = ws + off;
        off = (off + bytes + 255) & ~(size_t)255;
        return p;
    };
    int*    col_src = (int*)alloc((size_t)ET * 4);
    int*    counts  = (int*)alloc((size_t)N * 4);
    int*    row_ptr = (int*)alloc((size_t)(N + 1) * 4);
    float*  as_arr  = (float*)alloc((size_t)N * 4);
    float*  ad_arr  = (float*)alloc((size_t)N * 4);
    __half* hbuf    = (__half*)alloc((size_t)N * DD * 2);   // fp16 h (6.4 MB)
    float*  obuf    = (float*)alloc((size_t)N * DD * 4);    // fp32 activations
    (void)ws_size;

    // CSR-build temporaries alias the big layer buffers (both first written
    // by gemm/aggregate, which launch after the CSR build completes):
    int* rank     = (int*)hbuf;          // E ints (3.2 MB < 6.4 MB)
    int* scan_tmp = (int*)obuf;          // N ints
    int* blk      = scan_tmp + N;        // <=256 ints

    int gridE = (E + 255) / 256;
    int gridG = (N + GNPB - 1) / GNPB;
    int grid4 = (N + 3) / 4;
    int nb    = (N + 255) / 256;

    // CSR build (dst identical across the 3 layers -> build once per call)
    hipMemsetAsync(counts, 0, (size_t)N * 4, stream);
    count_kernel<<<gridE, 256, 0, stream>>>(ei, E, counts, rank);
    scan_blocks_kernel<<<nb, 256, 0, stream>>>(counts, scan_tmp, blk, N);
    scan_final_kernel<<<nb, 256, 0, stream>>>(counts, scan_tmp, blk, row_ptr,
                                              col_src, N, nb);
    scatter_kernel<<<gridE, 256, 0, stream>>>(ei, E, row_ptr, rank, col_src);

    // 3 GAT layers; head fused into the last aggregate.
    const float* cur = x;
    for (int L = 0; L < 3; ++L) {
        gemm_alpha_kernel<<<gridG, 256, 0, stream>>>(cur, W[L], as[L], ad[L],
                                                     hbuf, as_arr, ad_arr, N);
        if (L < 2) {
            aggregate_kernel<false><<<grid4, 256, 0, stream>>>(
                row_ptr, col_src, hbuf, as_arr, ad_arr, bv[L], obuf,
                nullptr, nullptr, N);
        } else {
            aggregate_kernel<true><<<grid4, 256, 0, stream>>>(
                row_ptr, col_src, hbuf, as_arr, ad_arr, bv[L], (float*)d_out,
                Wout, bout, N);
        }
        cur = obuf;
    }
}

// Round 13
// 305.137 us; speedup vs baseline: 1.9120x; 1.0228x over previous
//
#include <hip/hip_runtime.h>
#include <hip/hip_fp16.h>

#define DD 64
#define ATT_SLOPE 0.2f
#define ACT_SLOPE 0.01f
#define GNPB 32   // nodes per block in gemm (8 per wave)

// ---------------- CSR build ----------------
// edge_index delivered as int32, flat [2,E]: src = ei[e], dst = ei[E+e].
// Self-loops (GATConv add_self_loops=True) are added analytically: the scan
// gives each row one extra slot; scan_final writes the loop into the row's
// last slot. Per-node atomics (50k addresses) -- NOT few-bucket cursors:
// R10 showed 391-cursor atomics serialize catastrophically (282 us).

__global__ void count_kernel(const int* __restrict__ ei, int E,
                             int* __restrict__ counts, int* __restrict__ rank) {
    int e = blockIdx.x * blockDim.x + threadIdx.x;
    if (e >= E) return;
    int d = ei[E + e];
    rank[e] = atomicAdd(&counts[d], 1);
}

// Scan k1: per-block local exclusive scan of (counts[i]+1) -> scan_tmp,
// block total -> blk.
__global__ void scan_blocks_kernel(const int* __restrict__ counts,
                                   int* __restrict__ scan_tmp,
                                   int* __restrict__ blk, int n) {
    __shared__ int tile[256];
    int t = threadIdx.x;
    int i = blockIdx.x * 256 + t;
    int v = (i < n) ? (counts[i] + 1) : 0;     // +1 = self-loop slot
    tile[t] = v;
    __syncthreads();
    #pragma unroll
    for (int off = 1; off < 256; off <<= 1) {
        int add = (t >= off) ? tile[t - off] : 0;
        __syncthreads();
        tile[t] += add;
        __syncthreads();
    }
    if (i < n) scan_tmp[i] = tile[t] - v;
    if (t == 255) blk[blockIdx.x] = tile[255];
}

// Scan k2 (fused carry + fixup): every block redundantly scans the <=256
// block totals in LDS, picks its carry, writes row_ptr and the self-loop.
__global__ void scan_final_kernel(const int* __restrict__ counts,
                                  const int* __restrict__ scan_tmp,
                                  const int* __restrict__ blk,
                                  int* __restrict__ row_ptr,
                                  int* __restrict__ col_src, int n, int nb) {
    __shared__ int tile[256];
    int t = threadIdx.x;
    int v = (t < nb) ? blk[t] : 0;
    tile[t] = v;
    __syncthreads();
    #pragma unroll
    for (int off = 1; off < 256; off <<= 1) {
        int add = (t >= off) ? tile[t - off] : 0;
        __syncthreads();
        tile[t] += add;
        __syncthreads();
    }
    int carry = (blockIdx.x > 0) ? tile[blockIdx.x - 1] : 0;
    int i = blockIdx.x * 256 + t;
    if (i >= n) return;
    int excl = scan_tmp[i] + carry;
    int nxt = excl + counts[i] + 1;
    row_ptr[i + 1] = nxt;
    if (i == 0) row_ptr[0] = 0;
    col_src[nxt - 1] = i;            // self-loop occupies the row's last slot
}

// Atomic-free scatter of the E real edges via precomputed rank.
__global__ void scatter_kernel(const int* __restrict__ ei, int E,
                               const int* __restrict__ row_ptr,
                               const int* __restrict__ rank,
                               int* __restrict__ col_src) {
    int e = blockIdx.x * blockDim.x + threadIdx.x;
    if (e >= E) return;
    int s = ei[e], d = ei[E + e];
    col_src[row_ptr[d] + rank[e]] = s;
}

// ---------------- per-layer kernels ----------------

// h = in @ W.T. Block stages its 32 x-rows in LDS via coalesced float4
// VECTOR loads (deep MLP -- the R12 s_load x-path crawled at 429 GB/s on
// cold HBM); the FMA loop reads x back as ds_read_b128 with all 64 lanes
// at the same address (LDS broadcast, conflict-free). Lane j's weights =
// W row j, 256 B contiguous, L1-resident (R8-proven). 8 nodes per wave.
// h written fp16; fused alpha dots via batched shuffle reduction.
__global__ void gemm_alpha_kernel(
        const float* __restrict__ in, const float* __restrict__ W,
        const float* __restrict__ a_src, const float* __restrict__ a_dst,
        __half* __restrict__ h, float* __restrict__ as_out,
        float* __restrict__ ad_out, int n_nodes) {
    __shared__ float xin[GNPB * DD];   // 32 rows = 8 KB
    int t = threadIdx.x;
    int lane = t & 63;
    int w = t >> 6;
    int base = blockIdx.x * GNPB;

    // stage 32 rows = 512 float4, 256 threads -> 2 coalesced float4 each
    {
        float4* xin4 = (float4*)xin;
        const float4* src4 = (const float4*)in;
        int lim = n_nodes * (DD / 4);
        #pragma unroll
        for (int i = 0; i < (GNPB * DD / 4) / 256; ++i) {
            int idx = i * 256 + t;
            int gi = base * (DD / 4) + idx;
            xin4[idx] = (gi < lim) ? src4[gi]
                                   : make_float4(0.f, 0.f, 0.f, 0.f);
        }
    }
    __syncthreads();

    int n0 = base + w * 8;
    if (n0 >= n_nodes) return;

    float asl = a_src[lane], adl = a_dst[lane];
    const float* wrow = W + (size_t)lane * 64;

    if (n0 + 8 <= n_nodes) {
        float a[8] = {0.f, 0.f, 0.f, 0.f, 0.f, 0.f, 0.f, 0.f};
        #pragma unroll
        for (int kq = 0; kq < 16; ++kq) {
            float4 wv = *(const float4*)(wrow + kq * 4);   // L1 hit
            #pragma unroll
            for (int r = 0; r < 8; ++r) {
                // all lanes same address -> ds_read_b128 broadcast
                float4 xv = *(const float4*)&xin[(w * 8 + r) * DD + kq * 4];
                a[r] = fmaf(xv.x, wv.x, a[r]); a[r] = fmaf(xv.y, wv.y, a[r]);
                a[r] = fmaf(xv.z, wv.z, a[r]); a[r] = fmaf(xv.w, wv.w, a[r]);
            }
        }
        #pragma unroll
        for (int r = 0; r < 8; ++r)
            h[(size_t)(n0 + r) * 64 + lane] = __float2half(a[r]);
        float s[16];
        #pragma unroll
        for (int r = 0; r < 8; ++r) { s[2 * r] = a[r] * asl; s[2 * r + 1] = a[r] * adl; }
        #pragma unroll
        for (int m = 32; m >= 1; m >>= 1) {
            #pragma unroll
            for (int i = 0; i < 16; ++i) s[i] += __shfl_xor(s[i], m, 64);
        }
        if (lane == 0) {
            #pragma unroll
            for (int r = 0; r < 8; ++r) {
                as_out[n0 + r] = s[2 * r];
                ad_out[n0 + r] = s[2 * r + 1];
            }
        }
    } else {
        for (int r = 0; r < 8; ++r) {
            int node = n0 + r;
            if (node >= n_nodes) break;
            float acc = 0.f;
            #pragma unroll
            for (int kq = 0; kq < 16; ++kq) {
                float4 wv = *(const float4*)(wrow + kq * 4);
                float4 xv = *(const float4*)&xin[(w * 8 + r) * DD + kq * 4];
                acc = fmaf(xv.x, wv.x, acc); acc = fmaf(xv.y, wv.y, acc);
                acc = fmaf(xv.z, wv.z, acc); acc = fmaf(xv.w, wv.w, acc);
            }
            h[(size_t)node * 64 + lane] = __float2half(acc);
            float s1 = acc * asl, s2 = acc * adl;
            #pragma unroll
            for (int m = 32; m >= 1; m >>= 1) {
                s1 += __shfl_xor(s1, m, 64);
                s2 += __shfl_xor(s2, m, 64);
            }
            if (lane == 0) { as_out[node] = s1; ad_out[node] = s2; }
        }
    }
}

// One wave per dst node; 8 groups of 8 lanes. Lane u in a group holds a
// 16 B uint4 chunk (8 halves) of the 128 B fp16 row -> 8 edges in flight
// per wave. Depth-3 pipeline; fp32 accumulation.
template <bool FUSE_HEAD>
__global__ __launch_bounds__(256) void aggregate_kernel(
        const int* __restrict__ row_ptr, const int* __restrict__ col_src,
        const __half* __restrict__ h, const float* __restrict__ as_arr,
        const float* __restrict__ ad_arr, const float* __restrict__ b,
        float* __restrict__ out, const float* __restrict__ Wout,
        const float* __restrict__ bout, int n_nodes) {
    int t = threadIdx.x;
    int w = t >> 6, lane = t & 63;
    int node = blockIdx.x * 4 + w;
    if (node >= n_nodes) return;
    int g = lane >> 3, u = lane & 7;

    int beg = __builtin_amdgcn_readfirstlane(row_ptr[node]);
    int end = __builtin_amdgcn_readfirstlane(row_ptr[node + 1]);
    float adn = ad_arr[node];

    float acc[8] = {0.f, 0.f, 0.f, 0.f, 0.f, 0.f, 0.f, 0.f};
    float lsum = 0.f;
    int e = beg + g;

    uint4 rA = {0, 0, 0, 0}, rB = {0, 0, 0, 0};
    float aA = 0.f, aB = 0.f;
    if (e < end) {
        int s = col_src[e];
        aA = as_arr[s];
        rA = *(const uint4*)(h + (size_t)s * 64 + u * 8);
    }
    if (e + 8 < end) {
        int s = col_src[e + 8];
        aB = as_arr[s];
        rB = *(const uint4*)(h + (size_t)s * 64 + u * 8);
    }
    while (e < end) {
        int e2 = e + 16;
        uint4 rC = {0, 0, 0, 0}; float aC = 0.f;
        if (e2 < end) {
            int s = col_src[e2];
            aC = as_arr[s];
            rC = *(const uint4*)(h + (size_t)s * 64 + u * 8);
        }
        float lg = aA + adn;
        lg = (lg >= 0.f) ? lg : ATT_SLOPE * lg;
        float p = __expf(lg);
        lsum += p;
        float2 f0 = __half22float2(*(const __half2*)&rA.x);
        float2 f1 = __half22float2(*(const __half2*)&rA.y);
        float2 f2 = __half22float2(*(const __half2*)&rA.z);
        float2 f3 = __half22float2(*(const __half2*)&rA.w);
        acc[0] = fmaf(p, f0.x, acc[0]); acc[1] = fmaf(p, f0.y, acc[1]);
        acc[2] = fmaf(p, f1.x, acc[2]); acc[3] = fmaf(p, f1.y, acc[3]);
        acc[4] = fmaf(p, f2.x, acc[4]); acc[5] = fmaf(p, f2.y, acc[5]);
        acc[6] = fmaf(p, f3.x, acc[6]); acc[7] = fmaf(p, f3.y, acc[7]);
        rA = rB; aA = aB;
        rB = rC; aB = aC;
        e += 8;
    }
    // combine the 8 groups (lanes u, u+8, ..., u+56)
    #pragma unroll
    for (int m = 8; m <= 32; m <<= 1) {
        #pragma unroll
        for (int i = 0; i < 8; ++i) acc[i] += __shfl_xor(acc[i], m, 64);
        lsum += __shfl_xor(lsum, m, 64);
    }
    float inv = 1.f / lsum;
    const float4 b0 = *(const float4*)(b + u * 8);
    const float4 b1 = *(const float4*)(b + u * 8 + 4);
    float o[8];
    o[0] = acc[0] * inv + b0.x; o[1] = acc[1] * inv + b0.y;
    o[2] = acc[2] * inv + b0.z; o[3] = acc[3] * inv + b0.w;
    o[4] = acc[4] * inv + b1.x; o[5] = acc[5] * inv + b1.y;
    o[6] = acc[6] * inv + b1.z; o[7] = acc[7] * inv + b1.w;
    #pragma unroll
    for (int i = 0; i < 8; ++i) o[i] = (o[i] >= 0.f) ? o[i] : ACT_SLOPE * o[i];

    if (FUSE_HEAD) {
        const float4 w0 = *(const float4*)(Wout + u * 8);
        const float4 w1 = *(const float4*)(Wout + u * 8 + 4);
        float pd = o[0] * w0.x + o[1] * w0.y + o[2] * w0.z + o[3] * w0.w
                 + o[4] * w1.x + o[5] * w1.y + o[6] * w1.z + o[7] * w1.w;
        #pragma unroll
        for (int m = 1; m <= 4; m <<= 1) pd += __shfl_xor(pd, m, 64);
        if (lane == 0) out[node] = pd + bout[0];
    } else if (g == 0) {
        float4 v0 = {o[0], o[1], o[2], o[3]};
        float4 v1 = {o[4], o[5], o[6], o[7]};
        *(float4*)(out + (size_t)node * 64 + u * 8) = v0;
        *(float4*)(out + (size_t)node * 64 + u * 8 + 4) = v1;
    }
}

// ---------------- launch ----------------

extern "C" void kernel_launch(void* const* d_in, const int* in_sizes, int n_in,
                              void* d_out, int out_size, void* d_ws, size_t ws_size,
                              hipStream_t stream) {
    const float* x     = (const float*)d_in[0];
    const float* W[3]  = {(const float*)d_in[1], (const float*)d_in[5], (const float*)d_in[9]};
    const float* as[3] = {(const float*)d_in[2], (const float*)d_in[6], (const float*)d_in[10]};
    const float* ad[3] = {(const float*)d_in[3], (const float*)d_in[7], (const float*)d_in[11]};
    const float* bv[3] = {(const float*)d_in[4], (const float*)d_in[8], (const float*)d_in[12]};
    const float* Wout  = (const float*)d_in[13];
    const float* bout  = (const float*)d_in[14];
    const int*   ei    = (const int*)d_in[15];   // int64 reference -> delivered int32

    const int N  = in_sizes[0] / DD;
    const int E  = in_sizes[15] / 2;
    const int ET = E + N;

    // workspace layout (~25 MB; 256 B aligned)
    char* ws = (char*)d_ws;
    size_t off = 0;
    auto alloc = [&](size_t bytes) {
        void* p = ws + off;
        off = (off + bytes + 255) & ~(size_t)255;
        return p;
    };
    int*    col_src = (int*)alloc((size_t)ET * 4);
    int*    counts  = (int*)alloc((size_t)N * 4);
    int*    row_ptr = (int*)alloc((size_t)(N + 1) * 4);
    float*  as_arr  = (float*)alloc((size_t)N * 4);
    float*  ad_arr  = (float*)alloc((size_t)N * 4);
    __half* hbuf    = (__half*)alloc((size_t)N * DD * 2);   // fp16 h (6.4 MB)
    float*  obuf    = (float*)alloc((size_t)N * DD * 4);    // fp32 activations
    (void)ws_size;

    // CSR-build temporaries alias the big layer buffers (both first written
    // by gemm/aggregate, which launch after the CSR build completes):
    int* rank     = (int*)hbuf;          // E ints (3.2 MB < 6.4 MB)
    int* scan_tmp = (int*)obuf;          // N ints
    int* blk      = scan_tmp + N;        // <=256 ints

    int gridE = (E + 255) / 256;
    int gridG = (N + GNPB - 1) / GNPB;
    int grid4 = (N + 3) / 4;
    int nb    = (N + 255) / 256;

    // CSR build (dst identical across the 3 layers -> build once per call)
    hipMemsetAsync(counts, 0, (size_t)N * 4, stream);
    count_kernel<<<gridE, 256, 0, stream>>>(ei, E, counts, rank);
    scan_blocks_kernel<<<nb, 256, 0, stream>>>(counts, scan_tmp, blk, N);
    scan_final_kernel<<<nb, 256, 0, stream>>>(counts, scan_tmp, blk, row_ptr,
                                              col_src, N, nb);
    scatter_kernel<<<gridE, 256, 0, stream>>>(ei, E, row_ptr, rank, col_src);

    // 3 GAT layers; head fused into the last aggregate.
    const float* cur = x;
    for (int L = 0; L < 3; ++L) {
        gemm_alpha_kernel<<<gridG, 256, 0, stream>>>(cur, W[L], as[L], ad[L],
                                                     hbuf, as_arr, ad_arr, N);
        if (L < 2) {
            aggregate_kernel<false><<<grid4, 256, 0, stream>>>(
                row_ptr, col_src, hbuf, as_arr, ad_arr, bv[L], obuf,
                nullptr, nullptr, N);
        } else {
            aggregate_kernel<true><<<grid4, 256, 0, stream>>>(
                row_ptr, col_src, hbuf, as_arr, ad_arr, bv[L], (float*)d_out,
                Wout, bout, N);
        }
        cur = obuf;
    }
}